// Round 4
// baseline (299.236 us; speedup 1.0000x reference)
//
#include <hip/hip_runtime.h>
#include <math.h>

#define NLAB 8
#define BATCH 16
// acc layout per batch (floats):
//   [0..27] emb sums L1..7 x4ch | [28..34] cnt_k L1..7 | [35..40] cnt_i L2..7
//   [41..46] agg sums L2..7
#define S_OFF  0
#define CK_OFF 28
#define CI_OFF 35
#define AG_OFF 41
#define ACC_PER_B 48
#define CNT_IDX (BATCH * ACC_PER_B)            // acc[768]: arrival counter (uint)
#define ACC_ZERO_BYTES ((CNT_IDX + 1) * 4)
#define LAB_OFFSET 4096                        // label byte-cache offset in d_ws
#define GRID_X 64                              // 64x16 = 1024 blocks = 4/CU

__device__ __forceinline__ float wave_reduce(float v) {
#pragma unroll
  for (int off = 32; off > 0; off >>= 1) v += __shfl_xor(v, off, 64);
  return v;
}

// ===================== pass 1: segment sums =====================
// Tile = 1024 contiguous px per block-iteration; a wave owns 256 px as 4
// groups of 64 (lane-contiguous -> 1KB dwordx4 / 256B dword per instr).
// Depth-2 register pipeline: tile B's loads are issued BEFORE tile A is
// consumed, so each wave keeps a full tile (~80 cache lines) in flight.
// (R3 had ~1 line/wave in flight -> 590 GB/s latency wall at 94 us.)

struct AccTile {
  float4 e0, e1, e2, e3;
  int    v0, v1, v2, v3;
  float  q0, q1, q2, q3;
  float  u0, u1, u2, u3;
  int    p0;
};

__device__ __forceinline__ AccTile acc_issue(
    const float4* __restrict__ e, const int* __restrict__ ip,
    const float* __restrict__ kp, const float* __restrict__ tp,
    int t, int wid, int lane)
{
  AccTile T;
  T.p0 = (t << 10) + (wid << 8) + lane;
  T.e0 = e[T.p0];       T.e1 = e[T.p0 + 64];
  T.e2 = e[T.p0 + 128]; T.e3 = e[T.p0 + 192];
  T.v0 = ip[T.p0];       T.v1 = ip[T.p0 + 64];
  T.v2 = ip[T.p0 + 128]; T.v3 = ip[T.p0 + 192];
  T.q0 = kp[T.p0];       T.q1 = kp[T.p0 + 64];
  T.q2 = kp[T.p0 + 128]; T.q3 = kp[T.p0 + 192];
  T.u0 = tp[T.p0];       T.u1 = tp[T.p0 + 64];
  T.u2 = tp[T.p0 + 128]; T.u3 = tp[T.p0 + 192];
  return T;
}

__device__ __forceinline__ void acc_process(
    const AccTile& T, unsigned char* __restrict__ lb, int use_cache,
    float (&s)[28], int (&ck)[7], int (&ci)[6])
{
  int lab0 = (T.u0 > 0.5f) ? (T.v0 & 7) : 0;
  int lab1 = (T.u1 > 0.5f) ? (T.v1 & 7) : 0;
  int lab2 = (T.u2 > 0.5f) ? (T.v2 & 7) : 0;
  int lab3 = (T.u3 > 0.5f) ? (T.v3 & 7) : 0;
  if (use_cache) {
    lb[T.p0]       = (unsigned char)lab0;
    lb[T.p0 + 64]  = (unsigned char)lab1;
    lb[T.p0 + 128] = (unsigned char)lab2;
    lb[T.p0 + 192] = (unsigned char)lab3;
  }
  int lk0 = (T.q0 > 0.5f) ? lab0 : 8;          // 8 = sentinel, matches no l
  int lk1 = (T.q1 > 0.5f) ? lab1 : 8;
  int lk2 = (T.q2 > 0.5f) ? lab2 : 8;
  int lk3 = (T.q3 > 0.5f) ? lab3 : 8;

#pragma unroll
  for (int l = 1; l < NLAB; ++l) {
    bool h0 = (lk0 == l), h1 = (lk1 == l), h2 = (lk2 == l), h3 = (lk3 == l);
    ck[l - 1] += __popcll(__ballot(h0)) + __popcll(__ballot(h1)) +
                 __popcll(__ballot(h2)) + __popcll(__ballot(h3));
    float m0 = h0 ? 1.f : 0.f, m1 = h1 ? 1.f : 0.f;
    float m2 = h2 ? 1.f : 0.f, m3 = h3 ? 1.f : 0.f;
    const int o = (l - 1) * 4;
    s[o + 0] = fmaf(m0, T.e0.x, fmaf(m1, T.e1.x, fmaf(m2, T.e2.x, fmaf(m3, T.e3.x, s[o + 0]))));
    s[o + 1] = fmaf(m0, T.e0.y, fmaf(m1, T.e1.y, fmaf(m2, T.e2.y, fmaf(m3, T.e3.y, s[o + 1]))));
    s[o + 2] = fmaf(m0, T.e0.z, fmaf(m1, T.e1.z, fmaf(m2, T.e2.z, fmaf(m3, T.e3.z, s[o + 2]))));
    s[o + 3] = fmaf(m0, T.e0.w, fmaf(m1, T.e1.w, fmaf(m2, T.e2.w, fmaf(m3, T.e3.w, s[o + 3]))));
  }
#pragma unroll
  for (int l = 2; l < NLAB; ++l) {
    ci[l - 2] += __popcll(__ballot(lab0 == l)) + __popcll(__ballot(lab1 == l)) +
                 __popcll(__ballot(lab2 == l)) + __popcll(__ballot(lab3 == l));
  }
}

__global__ __launch_bounds__(256, 4) void k_accum(
    const float4* __restrict__ emb, const int* __restrict__ inst,
    const float* __restrict__ ker, const float* __restrict__ tmk,
    float* __restrict__ acc, unsigned char* __restrict__ labc,
    int P, int use_cache)
{
  const int b = blockIdx.y;
  const size_t base = (size_t)b * P;
  const float4* e  = emb + base;
  const int*    ip = inst + base;
  const float*  kp = ker + base;
  const float*  tp = tmk + base;
  unsigned char* lb = labc + base;

  float s[28];
#pragma unroll
  for (int k = 0; k < 28; ++k) s[k] = 0.f;
  int ck[7] = {0, 0, 0, 0, 0, 0, 0};
  int ci[6] = {0, 0, 0, 0, 0, 0};

  const int lane = threadIdx.x & 63;
  const int wid  = threadIdx.x >> 6;
  const int ntiles = P >> 10;
  const int stride = gridDim.x;

  // depth-2 ping-pong pipeline (no register copies between pending sets)
  int t = blockIdx.x;
  if (t < ntiles) {
    AccTile A = acc_issue(e, ip, kp, tp, t, wid, lane);
    for (;;) {
      int tB = t + stride;
      if (tB >= ntiles) { acc_process(A, lb, use_cache, s, ck, ci); break; }
      AccTile Bt = acc_issue(e, ip, kp, tp, tB, wid, lane);
      acc_process(A, lb, use_cache, s, ck, ci);
      int tA = tB + stride;
      if (tA >= ntiles) { acc_process(Bt, lb, use_cache, s, ck, ci); break; }
      A = acc_issue(e, ip, kp, tp, tA, wid, lane);
      acc_process(Bt, lb, use_cache, s, ck, ci);
      t = tA;
    }
  }

  // general-P tail (P % 1024 != 0): rare slow path, direct atomics
  if (blockIdx.x == 0) {
    for (int p = (ntiles << 10) + (int)threadIdx.x; p < P; p += (int)blockDim.x) {
      int lab = (tp[p] > 0.5f) ? (ip[p] & 7) : 0;
      float kr = kp[p];
      float4 ev = e[p];
      if (lab >= 1 && kr > 0.5f) {
        atomicAdd(&acc[b * ACC_PER_B + (lab - 1) * 4 + 0], ev.x);
        atomicAdd(&acc[b * ACC_PER_B + (lab - 1) * 4 + 1], ev.y);
        atomicAdd(&acc[b * ACC_PER_B + (lab - 1) * 4 + 2], ev.z);
        atomicAdd(&acc[b * ACC_PER_B + (lab - 1) * 4 + 3], ev.w);
        atomicAdd(&acc[b * ACC_PER_B + CK_OFF + lab - 1], 1.f);
      }
      if (lab >= 2) atomicAdd(&acc[b * ACC_PER_B + CI_OFF + lab - 2], 1.f);
    }
  }

  // stage-major butterfly -> LDS -> one atomic per block per slot
#pragma unroll
  for (int off = 32; off > 0; off >>= 1) {
    float tsh[28];
#pragma unroll
    for (int k = 0; k < 28; ++k) tsh[k] = __shfl_xor(s[k], off, 64);
#pragma unroll
    for (int k = 0; k < 28; ++k) s[k] += tsh[k];
  }

  __shared__ float redf[4][28];
  __shared__ int   redi[4][13];
  if (lane == 0) {
#pragma unroll
    for (int k = 0; k < 28; ++k) redf[wid][k] = s[k];
#pragma unroll
    for (int k = 0; k < 7; ++k) redi[wid][k] = ck[k];
#pragma unroll
    for (int k = 0; k < 6; ++k) redi[wid][7 + k] = ci[k];
  }
  __syncthreads();
  if (threadIdx.x < 28) {
    float v = redf[0][threadIdx.x] + redf[1][threadIdx.x] +
              redf[2][threadIdx.x] + redf[3][threadIdx.x];
    atomicAdd(acc + b * ACC_PER_B + S_OFF + threadIdx.x, v);
  } else if (threadIdx.x >= 32 && threadIdx.x < 32 + 13) {
    int j = threadIdx.x - 32;                  // 0..6 = ck, 7..12 = ci
    int v = redi[0][j] + redi[1][j] + redi[2][j] + redi[3][j];
    atomicAdd(acc + b * ACC_PER_B + CK_OFF + j, (float)v);
  }
}

// ===================== pass 2: aggregation + folded finalize =====================

struct AggTile {
  float4 e0, e1, e2, e3;
  int    l0, l1, l2, l3;     // cached label bytes (use_cache)
  int    v0, v1, v2, v3;     // raw inst (no cache)
  float  u0, u1, u2, u3;     // raw tm   (no cache)
  int    p0;
};

__device__ __forceinline__ AggTile agg_issue(
    const float4* __restrict__ e, const unsigned char* __restrict__ lb,
    const int* __restrict__ ip, const float* __restrict__ tp,
    int t, int wid, int lane, int use_cache)
{
  AggTile T;
  T.p0 = (t << 10) + (wid << 8) + lane;
  T.e0 = e[T.p0];       T.e1 = e[T.p0 + 64];
  T.e2 = e[T.p0 + 128]; T.e3 = e[T.p0 + 192];
  if (use_cache) {
    T.l0 = lb[T.p0];       T.l1 = lb[T.p0 + 64];
    T.l2 = lb[T.p0 + 128]; T.l3 = lb[T.p0 + 192];
  } else {
    T.v0 = ip[T.p0];       T.v1 = ip[T.p0 + 64];
    T.v2 = ip[T.p0 + 128]; T.v3 = ip[T.p0 + 192];
    T.u0 = tp[T.p0];       T.u1 = tp[T.p0 + 64];
    T.u2 = tp[T.p0 + 128]; T.u3 = tp[T.p0 + 192];
  }
  return T;
}

__device__ __forceinline__ void agg_process(
    const AggTile& T, const float4 (&smu)[NLAB], int use_cache, float (&ag)[6])
{
  int lab0 = use_cache ? T.l0 : ((T.u0 > 0.5f) ? (T.v0 & 7) : 0);
  int lab1 = use_cache ? T.l1 : ((T.u1 > 0.5f) ? (T.v1 & 7) : 0);
  int lab2 = use_cache ? T.l2 : ((T.u2 > 0.5f) ? (T.v2 & 7) : 0);
  int lab3 = use_cache ? T.l3 : ((T.u3 > 0.5f) ? (T.v3 & 7) : 0);
#pragma unroll
  for (int i = 0; i < 4; ++i) {
    int lab = (i == 0) ? lab0 : (i == 1) ? lab1 : (i == 2) ? lab2 : lab3;
    float4 ev = (i == 0) ? T.e0 : (i == 1) ? T.e1 : (i == 2) ? T.e2 : T.e3;
    float4 mv = smu[lab];
    float dx = ev.x - mv.x, dy = ev.y - mv.y;
    float dz = ev.z - mv.z, dw = ev.w - mv.w;
    float d = sqrtf(dx * dx + dy * dy + dz * dz + dw * dw);
    float tt = fmaxf(d - 0.5f, 0.f);           // DELTA_V
    float term = logf(fmaf(tt, tt, 1.f));
#pragma unroll
    for (int l = 0; l < 6; ++l) ag[l] += (lab == l + 2) ? term : 0.f;
  }
}

__global__ __launch_bounds__(256, 4) void k_agg(
    const float4* __restrict__ emb, const int* __restrict__ inst,
    const float* __restrict__ tmk, const unsigned char* __restrict__ labc,
    float* __restrict__ acc, float* __restrict__ out,
    int P, int use_cache, int nblocks)
{
  const int b = blockIdx.y;
  const size_t base = (size_t)b * P;
  __shared__ float4 smu_s[NLAB];
  const float* accB = acc + b * ACC_PER_B;
  if (threadIdx.x < NLAB) {
    int l = threadIdx.x;
    float4 m = make_float4(0.f, 0.f, 0.f, 0.f);
    if (l > 0) {
      float inv = 1.f / fmaxf(accB[CK_OFF + l - 1], 1.f);
      m = make_float4(accB[S_OFF + (l - 1) * 4 + 0] * inv,
                      accB[S_OFF + (l - 1) * 4 + 1] * inv,
                      accB[S_OFF + (l - 1) * 4 + 2] * inv,
                      accB[S_OFF + (l - 1) * 4 + 3] * inv);
    }
    smu_s[l] = m;
  }
  __syncthreads();
  float4 smu[NLAB];                            // per-thread copy -> VGPRs, no LDS in loop
#pragma unroll
  for (int l = 0; l < NLAB; ++l) smu[l] = smu_s[l];

  const float4* e = emb + base;
  const int*    ip = inst + base;
  const float*  tp = tmk + base;
  const unsigned char* lb = labc + base;

  float ag[6] = {0.f, 0.f, 0.f, 0.f, 0.f, 0.f};
  const int lane = threadIdx.x & 63;
  const int wid  = threadIdx.x >> 6;
  const int ntiles = P >> 10;
  const int stride = gridDim.x;

  int t = blockIdx.x;
  if (t < ntiles) {
    AggTile A = agg_issue(e, lb, ip, tp, t, wid, lane, use_cache);
    for (;;) {
      int tB = t + stride;
      if (tB >= ntiles) { agg_process(A, smu, use_cache, ag); break; }
      AggTile Bt = agg_issue(e, lb, ip, tp, tB, wid, lane, use_cache);
      agg_process(A, smu, use_cache, ag);
      int tA = tB + stride;
      if (tA >= ntiles) { agg_process(Bt, smu, use_cache, ag); break; }
      A = agg_issue(e, lb, ip, tp, tA, wid, lane, use_cache);
      agg_process(Bt, smu, use_cache, ag);
      t = tA;
    }
  }

  if (blockIdx.x == 0) {                       // general-P tail
    for (int p = (ntiles << 10) + (int)threadIdx.x; p < P; p += (int)blockDim.x) {
      int lab = (tp[p] > 0.5f) ? (ip[p] & 7) : 0;
      if (lab >= 2) {
        float4 ev = e[p]; float4 mv = smu[lab];
        float dx = ev.x - mv.x, dy = ev.y - mv.y;
        float dz = ev.z - mv.z, dw = ev.w - mv.w;
        float d = sqrtf(dx * dx + dy * dy + dz * dz + dw * dw);
        float tt = fmaxf(d - 0.5f, 0.f);
        atomicAdd(&acc[b * ACC_PER_B + AG_OFF + lab - 2], logf(fmaf(tt, tt, 1.f)));
      }
    }
  }

#pragma unroll
  for (int off = 32; off > 0; off >>= 1) {
    float tsh[6];
#pragma unroll
    for (int k = 0; k < 6; ++k) tsh[k] = __shfl_xor(ag[k], off, 64);
#pragma unroll
    for (int k = 0; k < 6; ++k) ag[k] += tsh[k];
  }
  __shared__ float redf[4][6];
  if (lane == 0) {
#pragma unroll
    for (int k = 0; k < 6; ++k) redf[wid][k] = ag[k];
  }
  __syncthreads();
  if (threadIdx.x < 6) {
    float v = redf[0][threadIdx.x] + redf[1][threadIdx.x] +
              redf[2][threadIdx.x] + redf[3][threadIdx.x];
    atomicAdd(acc + b * ACC_PER_B + AG_OFF + threadIdx.x, v);
  }

  // ---- folded finalize: last-arriving block computes the loss ----
  // Release RMW on the arrival counter orders our prior device-scope atomics
  // without the full-L2-writeback __threadfence() R3 paid per block.
  __syncthreads();
  __shared__ int amlast;
  if (threadIdx.x == 0) {
    unsigned int* cnt = (unsigned int*)(acc + CNT_IDX);
    unsigned int old = __hip_atomic_fetch_add(cnt, 1u, __ATOMIC_ACQ_REL,
                                              __HIP_MEMORY_SCOPE_AGENT);
    amlast = (old == (unsigned int)(nblocks - 1)) ? 1 : 0;
  }
  __syncthreads();
  if (amlast && threadIdx.x < 64) {
    float loss = 0.f;
    if (threadIdx.x < BATCH) {
      const float* a = acc + threadIdx.x * ACC_PER_B;
      float av[47];
#pragma unroll
      for (int k = 0; k < 47; ++k)
        av[k] = __hip_atomic_load(&a[k], __ATOMIC_RELAXED, __HIP_MEMORY_SCOPE_AGENT);
      float mu[NLAB][4];
#pragma unroll
      for (int c = 0; c < 4; ++c) mu[0][c] = 0.f;
#pragma unroll
      for (int l = 1; l < NLAB; ++l) {
        float inv = 1.f / fmaxf(av[CK_OFF + l - 1], 1.f);
#pragma unroll
        for (int c = 0; c < 4; ++c) mu[l][c] = av[S_OFF + (l - 1) * 4 + c] * inv;
      }
      float l_agg = 0.f;
#pragma unroll
      for (int l = 2; l < NLAB; ++l)
        l_agg += av[AG_OFF + l - 2] / fmaxf(av[CI_OFF + l - 2], 1.f);
      l_agg *= (1.f / 6.f);
      float ssum = 0.f;
      for (int i = 1; i < NLAB; ++i)
        for (int j = 1; j < NLAB; ++j) {
          if (i == j) continue;
          float dx = mu[i][0] - mu[j][0], dy = mu[i][1] - mu[j][1];
          float dz = mu[i][2] - mu[j][2], dw = mu[i][3] - mu[j][3];
          float dd = sqrtf(dx * dx + dy * dy + dz * dz + dw * dw);
          float tt = fmaxf(3.0f - dd, 0.f);    // 2*DELTA_D
          ssum += logf(fmaf(tt, tt, 1.f));
        }
      float l_dis = ssum / 42.f;
      float rsum = 0.f;
#pragma unroll
      for (int l = 1; l < NLAB; ++l) {
        float n = sqrtf(mu[l][0] * mu[l][0] + mu[l][1] * mu[l][1] +
                        mu[l][2] * mu[l][2] + mu[l][3] * mu[l][3]);
        rsum += logf(n + 1.f);
      }
      float l_reg = rsum * (0.001f / NLAB);
      loss = l_agg + l_dis + l_reg;
    }
    loss = wave_reduce(loss);
    if (threadIdx.x == 0) out[0] = loss * (1.f / BATCH);   // LOSS_WEIGHT = 1
  }
}

extern "C" void kernel_launch(void* const* d_in, const int* in_sizes, int n_in,
                              void* d_out, int out_size, void* d_ws, size_t ws_size,
                              hipStream_t stream) {
  const float4* emb  = (const float4*)d_in[0];
  const int*    inst = (const int*)d_in[1];
  const float*  ker  = (const float*)d_in[2];
  const float*  tmk  = (const float*)d_in[3];
  float* out = (float*)d_out;

  const int total = in_sizes[1];       // B*H*W
  const int P = total / BATCH;

  float* acc = (float*)d_ws;
  unsigned char* labc = (unsigned char*)d_ws + LAB_OFFSET;
  const size_t need = (size_t)LAB_OFFSET + (size_t)total;
  const int use_cache = (ws_size >= need) ? 1 : 0;

  // d_ws re-poisoned to 0xAA each launch: zero accumulators + arrival counter
  hipMemsetAsync(d_ws, 0, ACC_ZERO_BYTES, stream);

  dim3 grid(GRID_X, BATCH);            // 1024 blocks = 4/CU, single round
  k_accum<<<grid, 256, 0, stream>>>(emb, inst, ker, tmk, acc, labc, P, use_cache);
  k_agg  <<<grid, 256, 0, stream>>>(emb, inst, tmk, labc, acc, out, P, use_cache,
                                    GRID_X * BATCH);
}

// Round 5
// 287.992 us; speedup vs baseline: 1.0390x; 1.0390x over previous
//
#include <hip/hip_runtime.h>
#include <math.h>

#define NLAB 8
#define BATCH 16
// acc layout per batch (floats):
//   [0..27] emb sums L1..7 x4ch | [28..34] cnt_k L1..7 | [35..40] cnt_i L2..7
//   [41..46] agg sums L2..7
#define S_OFF  0
#define CK_OFF 28
#define CI_OFF 35
#define AG_OFF 41
#define ACC_PER_B 48
#define CNT_IDX (BATCH * ACC_PER_B)            // acc[768]: arrival counter (uint)
#define ACC_ZERO_BYTES ((CNT_IDX + 1) * 4)
#define LAB_OFFSET 4096                        // label byte-cache offset in d_ws
#define GX_ACC 32                              // 32x16 = 512 blocks = 2/CU (58KB LDS)
#define GX_AGG 48                              // 48x16 = 768 blocks = 3/CU (49KB LDS)

__device__ __forceinline__ float wave_reduce(float v) {
#pragma unroll
  for (int off = 32; off > 0; off >>= 1) v += __shfl_xor(v, off, 64);
  return v;
}

// Async global->LDS DMA. In-flight count decoupled from the register
// allocator (R2-R4 evidence: allocator clamps register MLP to ~1 load/wave,
// VGPR pinned at 48, explicit reg pipeline spilled to scratch instead).
// LDS dest is wave-uniform base + lane*size; gsrc is per-lane.
__device__ __forceinline__ void dma16(const void* g, void* l) {
  __builtin_amdgcn_global_load_lds((const __attribute__((address_space(1))) void*)g,
                                   (__attribute__((address_space(3))) void*)l,
                                   16, 0, 0);
}
__device__ __forceinline__ void dma4(const void* g, void* l) {
  __builtin_amdgcn_global_load_lds((const __attribute__((address_space(1))) void*)g,
                                   (__attribute__((address_space(3))) void*)l,
                                   4, 0, 0);
}

// ===================== pass 1: segment sums =====================
// Chunk = 256 contiguous px per wave. LDS buffer layout (7168 B):
//   [0,4096) emb  [4096,5120) inst  [5120,6144) ker  [6144,7168) tm
// Lane i processes px 4i..4i+3 (LDS reads are conflict-cheap; global side is
// perfectly coalesced by the DMA). Double-buffered, no barriers in the loop.

__global__ __launch_bounds__(256, 2) void k_accum(
    const float4* __restrict__ emb, const int* __restrict__ inst,
    const float* __restrict__ ker, const float* __restrict__ tmk,
    float* __restrict__ acc, unsigned int* __restrict__ labc32,
    int P, int use_cache)
{
  __shared__ __align__(16) unsigned char lds[4][2][7168];
  const int b = blockIdx.y;
  const size_t base = (size_t)b * P;
  const char* ge = (const char*)(emb + base);
  const char* gi = (const char*)(inst + base);
  const char* gk = (const char*)(ker + base);
  const char* gt = (const char*)(tmk + base);
  unsigned int* lb32 = labc32 + (base >> 2);

  const int lane = threadIdx.x & 63;
  const int wid  = threadIdx.x >> 6;

  float s[28];
#pragma unroll
  for (int k = 0; k < 28; ++k) s[k] = 0.f;
  int ck[7] = {0, 0, 0, 0, 0, 0, 0};
  int ci[6] = {0, 0, 0, 0, 0, 0};

  const int nch = P >> 8;                      // 256-px chunks
  const int wgid = blockIdx.x * 4 + wid;
  const int wstride = gridDim.x * 4;

#define ACC_ISSUE(c, bb) do {                                              \
    unsigned char* L = lds[wid][bb];                                       \
    const char* gE = ge + ((size_t)(c) << 12) + lane * 16;                 \
    dma16(gE,          L);                                                 \
    dma16(gE + 1024,   L + 1024);                                          \
    dma16(gE + 2048,   L + 2048);                                          \
    dma16(gE + 3072,   L + 3072);                                          \
    dma16(gi + ((size_t)(c) << 10) + lane * 16, L + 4096);                 \
    dma16(gk + ((size_t)(c) << 10) + lane * 16, L + 5120);                 \
    dma16(gt + ((size_t)(c) << 10) + lane * 16, L + 6144);                 \
  } while (0)

#define ACC_PROCESS(c, bb) do {                                            \
    const unsigned char* L = lds[wid][bb];                                 \
    int4   iv = ((const int4*)(L + 4096))[lane];                           \
    float4 kv = ((const float4*)(L + 5120))[lane];                         \
    float4 uv = ((const float4*)(L + 6144))[lane];                         \
    float4 e0 = ((const float4*)L)[4 * lane + 0];                          \
    float4 e1 = ((const float4*)L)[4 * lane + 1];                          \
    float4 e2 = ((const float4*)L)[4 * lane + 2];                          \
    float4 e3 = ((const float4*)L)[4 * lane + 3];                          \
    int lab0 = (uv.x > 0.5f) ? (iv.x & 7) : 0;                             \
    int lab1 = (uv.y > 0.5f) ? (iv.y & 7) : 0;                             \
    int lab2 = (uv.z > 0.5f) ? (iv.z & 7) : 0;                             \
    int lab3 = (uv.w > 0.5f) ? (iv.w & 7) : 0;                             \
    if (use_cache)                                                         \
      lb32[((c) << 6) + lane] = (unsigned)lab0 | ((unsigned)lab1 << 8) |   \
                                ((unsigned)lab2 << 16) | ((unsigned)lab3 << 24); \
    int lk0 = (kv.x > 0.5f) ? lab0 : 8;                                    \
    int lk1 = (kv.y > 0.5f) ? lab1 : 8;                                    \
    int lk2 = (kv.z > 0.5f) ? lab2 : 8;                                    \
    int lk3 = (kv.w > 0.5f) ? lab3 : 8;                                    \
    _Pragma("unroll")                                                      \
    for (int l = 1; l < NLAB; ++l) {                                       \
      bool h0 = (lk0 == l), h1 = (lk1 == l), h2 = (lk2 == l), h3 = (lk3 == l); \
      ck[l - 1] += __popcll(__ballot(h0)) + __popcll(__ballot(h1)) +       \
                   __popcll(__ballot(h2)) + __popcll(__ballot(h3));        \
      float m0 = h0 ? 1.f : 0.f, m1 = h1 ? 1.f : 0.f;                      \
      float m2 = h2 ? 1.f : 0.f, m3 = h3 ? 1.f : 0.f;                      \
      const int o = (l - 1) * 4;                                           \
      s[o + 0] = fmaf(m0, e0.x, fmaf(m1, e1.x, fmaf(m2, e2.x, fmaf(m3, e3.x, s[o + 0])))); \
      s[o + 1] = fmaf(m0, e0.y, fmaf(m1, e1.y, fmaf(m2, e2.y, fmaf(m3, e3.y, s[o + 1])))); \
      s[o + 2] = fmaf(m0, e0.z, fmaf(m1, e1.z, fmaf(m2, e2.z, fmaf(m3, e3.z, s[o + 2])))); \
      s[o + 3] = fmaf(m0, e0.w, fmaf(m1, e1.w, fmaf(m2, e2.w, fmaf(m3, e3.w, s[o + 3])))); \
    }                                                                      \
    _Pragma("unroll")                                                      \
    for (int l = 2; l < NLAB; ++l)                                         \
      ci[l - 2] += __popcll(__ballot(lab0 == l)) + __popcll(__ballot(lab1 == l)) + \
                   __popcll(__ballot(lab2 == l)) + __popcll(__ballot(lab3 == l));  \
  } while (0)

  if (wgid < nch) {
    int cur = wgid, bufc = 0;
    ACC_ISSUE(cur, 0);
    for (;;) {
      int nxt = cur + wstride;
      if (nxt < nch) {
        ACC_ISSUE(nxt, bufc ^ 1);
        asm volatile("s_waitcnt vmcnt(7)" ::: "memory");
        ACC_PROCESS(cur, bufc);
        cur = nxt; bufc ^= 1;
      } else {
        asm volatile("s_waitcnt vmcnt(0)" ::: "memory");
        ACC_PROCESS(cur, bufc);
        break;
      }
    }
  }

  // general-P tail (P % 256 != 0): rare slow path, direct atomics
  if (blockIdx.x == 0) {
    const float4* e = emb + base;
    for (int p = (nch << 8) + (int)threadIdx.x; p < P; p += (int)blockDim.x) {
      int lab = (tmk[base + p] > 0.5f) ? (inst[base + p] & 7) : 0;
      float kr = ker[base + p];
      float4 ev = e[p];
      if (lab >= 1 && kr > 0.5f) {
        atomicAdd(&acc[b * ACC_PER_B + (lab - 1) * 4 + 0], ev.x);
        atomicAdd(&acc[b * ACC_PER_B + (lab - 1) * 4 + 1], ev.y);
        atomicAdd(&acc[b * ACC_PER_B + (lab - 1) * 4 + 2], ev.z);
        atomicAdd(&acc[b * ACC_PER_B + (lab - 1) * 4 + 3], ev.w);
        atomicAdd(&acc[b * ACC_PER_B + CK_OFF + lab - 1], 1.f);
      }
      if (lab >= 2) atomicAdd(&acc[b * ACC_PER_B + CI_OFF + lab - 2], 1.f);
    }
  }

  // stage-major butterfly -> LDS -> one atomic per block per slot
#pragma unroll
  for (int off = 32; off > 0; off >>= 1) {
    float tsh[28];
#pragma unroll
    for (int k = 0; k < 28; ++k) tsh[k] = __shfl_xor(s[k], off, 64);
#pragma unroll
    for (int k = 0; k < 28; ++k) s[k] += tsh[k];
  }

  __shared__ float redf[4][28];
  __shared__ int   redi[4][13];
  if (lane == 0) {
#pragma unroll
    for (int k = 0; k < 28; ++k) redf[wid][k] = s[k];
#pragma unroll
    for (int k = 0; k < 7; ++k) redi[wid][k] = ck[k];
#pragma unroll
    for (int k = 0; k < 6; ++k) redi[wid][7 + k] = ci[k];
  }
  __syncthreads();
  if (threadIdx.x < 28) {
    float v = redf[0][threadIdx.x] + redf[1][threadIdx.x] +
              redf[2][threadIdx.x] + redf[3][threadIdx.x];
    atomicAdd(acc + b * ACC_PER_B + S_OFF + threadIdx.x, v);
  } else if (threadIdx.x >= 32 && threadIdx.x < 32 + 13) {
    int j = threadIdx.x - 32;                  // 0..6 = ck, 7..12 = ci
    int v = redi[0][j] + redi[1][j] + redi[2][j] + redi[3][j];
    atomicAdd(acc + b * ACC_PER_B + CK_OFF + j, (float)v);
  }
}

// ===================== pass 2: aggregation + folded finalize =====================
// LDS buffer (6144 B): [0,4096) emb; cache: [4096,4352) labels (256 B);
// no-cache: [4096,5120) inst, [5120,6144) tm.

__global__ __launch_bounds__(256, 3) void k_agg(
    const float4* __restrict__ emb, const int* __restrict__ inst,
    const float* __restrict__ tmk, const unsigned char* __restrict__ labc,
    float* __restrict__ acc, float* __restrict__ out,
    int P, int use_cache, int nblocks)
{
  __shared__ __align__(16) unsigned char lds[4][2][6144];
  const int b = blockIdx.y;
  const size_t base = (size_t)b * P;
  __shared__ float4 smu_s[NLAB];
  const float* accB = acc + b * ACC_PER_B;
  if (threadIdx.x < NLAB) {
    int l = threadIdx.x;
    float4 m = make_float4(0.f, 0.f, 0.f, 0.f);
    if (l > 0) {
      float inv = 1.f / fmaxf(accB[CK_OFF + l - 1], 1.f);
      m = make_float4(accB[S_OFF + (l - 1) * 4 + 0] * inv,
                      accB[S_OFF + (l - 1) * 4 + 1] * inv,
                      accB[S_OFF + (l - 1) * 4 + 2] * inv,
                      accB[S_OFF + (l - 1) * 4 + 3] * inv);
    }
    smu_s[l] = m;
  }
  __syncthreads();
  float4 smu[NLAB];
#pragma unroll
  for (int l = 0; l < NLAB; ++l) smu[l] = smu_s[l];

  const char* ge = (const char*)(emb + base);
  const char* gi = (const char*)(inst + base);
  const char* gt = (const char*)(tmk + base);
  const unsigned char* gl = labc + base;

  const int lane = threadIdx.x & 63;
  const int wid  = threadIdx.x >> 6;

  float ag[6] = {0.f, 0.f, 0.f, 0.f, 0.f, 0.f};
  const int nch = P >> 8;
  const int wgid = blockIdx.x * 4 + wid;
  const int wstride = gridDim.x * 4;

#define AGG_ISSUE(c, bb) do {                                              \
    unsigned char* L = lds[wid][bb];                                       \
    const char* gE = ge + ((size_t)(c) << 12) + lane * 16;                 \
    dma16(gE,          L);                                                 \
    dma16(gE + 1024,   L + 1024);                                          \
    dma16(gE + 2048,   L + 2048);                                          \
    dma16(gE + 3072,   L + 3072);                                          \
    if (use_cache) {                                                       \
      dma4(gl + ((size_t)(c) << 8) + lane * 4, L + 4096);                  \
    } else {                                                               \
      dma16(gi + ((size_t)(c) << 10) + lane * 16, L + 4096);               \
      dma16(gt + ((size_t)(c) << 10) + lane * 16, L + 5120);               \
    }                                                                      \
  } while (0)

#define AGG_PROCESS(c, bb) do {                                            \
    const unsigned char* L = lds[wid][bb];                                 \
    int lab0, lab1, lab2, lab3;                                            \
    if (use_cache) {                                                       \
      unsigned lw = ((const unsigned*)(L + 4096))[lane];                   \
      lab0 = lw & 255; lab1 = (lw >> 8) & 255;                             \
      lab2 = (lw >> 16) & 255; lab3 = (lw >> 24) & 255;                    \
    } else {                                                               \
      int4   iv = ((const int4*)(L + 4096))[lane];                         \
      float4 uv = ((const float4*)(L + 5120))[lane];                       \
      lab0 = (uv.x > 0.5f) ? (iv.x & 7) : 0;                               \
      lab1 = (uv.y > 0.5f) ? (iv.y & 7) : 0;                               \
      lab2 = (uv.z > 0.5f) ? (iv.z & 7) : 0;                               \
      lab3 = (uv.w > 0.5f) ? (iv.w & 7) : 0;                               \
    }                                                                      \
    _Pragma("unroll")                                                      \
    for (int j = 0; j < 4; ++j) {                                          \
      int lab = (j == 0) ? lab0 : (j == 1) ? lab1 : (j == 2) ? lab2 : lab3;\
      float4 ev = ((const float4*)L)[4 * lane + j];                        \
      float4 mv = smu[lab];                                                \
      float dx = ev.x - mv.x, dy = ev.y - mv.y;                            \
      float dz = ev.z - mv.z, dw = ev.w - mv.w;                            \
      float d = sqrtf(dx * dx + dy * dy + dz * dz + dw * dw);              \
      float tt = fmaxf(d - 0.5f, 0.f);             /* DELTA_V */           \
      float term = logf(fmaf(tt, tt, 1.f));                                \
      _Pragma("unroll")                                                    \
      for (int l = 0; l < 6; ++l) ag[l] += (lab == l + 2) ? term : 0.f;    \
    }                                                                      \
  } while (0)

  if (wgid < nch) {
    int cur = wgid, bufc = 0;
    AGG_ISSUE(cur, 0);
    for (;;) {
      int nxt = cur + wstride;
      if (nxt < nch) {
        AGG_ISSUE(nxt, bufc ^ 1);
        if (use_cache) asm volatile("s_waitcnt vmcnt(5)" ::: "memory");
        else           asm volatile("s_waitcnt vmcnt(6)" ::: "memory");
        AGG_PROCESS(cur, bufc);
        cur = nxt; bufc ^= 1;
      } else {
        asm volatile("s_waitcnt vmcnt(0)" ::: "memory");
        AGG_PROCESS(cur, bufc);
        break;
      }
    }
  }

  if (blockIdx.x == 0) {                       // general-P tail
    const float4* e = emb + base;
    for (int p = (nch << 8) + (int)threadIdx.x; p < P; p += (int)blockDim.x) {
      int lab = (tmk[base + p] > 0.5f) ? (inst[base + p] & 7) : 0;
      if (lab >= 2) {
        float4 ev = e[p]; float4 mv = smu[lab];
        float dx = ev.x - mv.x, dy = ev.y - mv.y;
        float dz = ev.z - mv.z, dw = ev.w - mv.w;
        float d = sqrtf(dx * dx + dy * dy + dz * dz + dw * dw);
        float tt = fmaxf(d - 0.5f, 0.f);
        atomicAdd(&acc[b * ACC_PER_B + AG_OFF + lab - 2], logf(fmaf(tt, tt, 1.f)));
      }
    }
  }

#pragma unroll
  for (int off = 32; off > 0; off >>= 1) {
    float tsh[6];
#pragma unroll
    for (int k = 0; k < 6; ++k) tsh[k] = __shfl_xor(ag[k], off, 64);
#pragma unroll
    for (int k = 0; k < 6; ++k) ag[k] += tsh[k];
  }
  __shared__ float redf[4][6];
  if (lane == 0) {
#pragma unroll
    for (int k = 0; k < 6; ++k) redf[wid][k] = ag[k];
  }
  __syncthreads();
  if (threadIdx.x < 6) {
    float v = redf[0][threadIdx.x] + redf[1][threadIdx.x] +
              redf[2][threadIdx.x] + redf[3][threadIdx.x];
    atomicAdd(acc + b * ACC_PER_B + AG_OFF + threadIdx.x, v);
  }

  // ---- folded finalize: last-arriving block computes the loss ----
  __syncthreads();
  __shared__ int amlast;
  if (threadIdx.x == 0) {
    unsigned int* cnt = (unsigned int*)(acc + CNT_IDX);
    unsigned int old = __hip_atomic_fetch_add(cnt, 1u, __ATOMIC_ACQ_REL,
                                              __HIP_MEMORY_SCOPE_AGENT);
    amlast = (old == (unsigned int)(nblocks - 1)) ? 1 : 0;
  }
  __syncthreads();
  if (amlast && threadIdx.x < 64) {
    float loss = 0.f;
    if (threadIdx.x < BATCH) {
      const float* a = acc + threadIdx.x * ACC_PER_B;
      float av[47];
#pragma unroll
      for (int k = 0; k < 47; ++k)
        av[k] = __hip_atomic_load(&a[k], __ATOMIC_RELAXED, __HIP_MEMORY_SCOPE_AGENT);
      float mu[NLAB][4];
#pragma unroll
      for (int c = 0; c < 4; ++c) mu[0][c] = 0.f;
#pragma unroll
      for (int l = 1; l < NLAB; ++l) {
        float inv = 1.f / fmaxf(av[CK_OFF + l - 1], 1.f);
#pragma unroll
        for (int c = 0; c < 4; ++c) mu[l][c] = av[S_OFF + (l - 1) * 4 + c] * inv;
      }
      float l_agg = 0.f;
#pragma unroll
      for (int l = 2; l < NLAB; ++l)
        l_agg += av[AG_OFF + l - 2] / fmaxf(av[CI_OFF + l - 2], 1.f);
      l_agg *= (1.f / 6.f);
      float ssum = 0.f;
      for (int i = 1; i < NLAB; ++i)
        for (int j = 1; j < NLAB; ++j) {
          if (i == j) continue;
          float dx = mu[i][0] - mu[j][0], dy = mu[i][1] - mu[j][1];
          float dz = mu[i][2] - mu[j][2], dw = mu[i][3] - mu[j][3];
          float dd = sqrtf(dx * dx + dy * dy + dz * dz + dw * dw);
          float tt = fmaxf(3.0f - dd, 0.f);    // 2*DELTA_D
          ssum += logf(fmaf(tt, tt, 1.f));
        }
      float l_dis = ssum / 42.f;
      float rsum = 0.f;
#pragma unroll
      for (int l = 1; l < NLAB; ++l) {
        float n = sqrtf(mu[l][0] * mu[l][0] + mu[l][1] * mu[l][1] +
                        mu[l][2] * mu[l][2] + mu[l][3] * mu[l][3]);
        rsum += logf(n + 1.f);
      }
      float l_reg = rsum * (0.001f / NLAB);
      loss = l_agg + l_dis + l_reg;
    }
    loss = wave_reduce(loss);
    if (threadIdx.x == 0) out[0] = loss * (1.f / BATCH);   // LOSS_WEIGHT = 1
  }
}

extern "C" void kernel_launch(void* const* d_in, const int* in_sizes, int n_in,
                              void* d_out, int out_size, void* d_ws, size_t ws_size,
                              hipStream_t stream) {
  const float4* emb  = (const float4*)d_in[0];
  const int*    inst = (const int*)d_in[1];
  const float*  ker  = (const float*)d_in[2];
  const float*  tmk  = (const float*)d_in[3];
  float* out = (float*)d_out;

  const int total = in_sizes[1];       // B*H*W
  const int P = total / BATCH;

  float* acc = (float*)d_ws;
  unsigned char* labc = (unsigned char*)d_ws + LAB_OFFSET;
  const size_t need = (size_t)LAB_OFFSET + (size_t)total;
  const int use_cache = (ws_size >= need && (P & 3) == 0) ? 1 : 0;

  // d_ws re-poisoned to 0xAA each launch: zero accumulators + arrival counter
  hipMemsetAsync(d_ws, 0, ACC_ZERO_BYTES, stream);

  dim3 ga(GX_ACC, BATCH);
  dim3 gb(GX_AGG, BATCH);
  k_accum<<<ga, 256, 0, stream>>>(emb, inst, ker, tmk, acc,
                                  (unsigned int*)labc, P, use_cache);
  k_agg  <<<gb, 256, 0, stream>>>(emb, inst, tmk, labc, acc, out, P, use_cache,
                                  GX_AGG * BATCH);
}